// Round 1
// baseline (453.027 us; speedup 1.0000x reference)
//
#include <hip/hip_runtime.h>
#include <hip/hip_bf16.h>

#define TT 16      // in_length
#define EE 32      // embedding size
#define HH 64      // encoder size
#define NGRP 32    // vehicles per group
#define CC 3       // classes

typedef __attribute__((ext_vector_type(8))) short short8;
typedef __attribute__((ext_vector_type(4))) float floatx4;

#define MFMA16(a, b, c) __builtin_amdgcn_mfma_f32_16x16x32_bf16((a), (b), (c), 0, 0, 0)

#define RLN2 1.4426950408889634f   // 1/ln2

__device__ __forceinline__ float leakyf(float x) { return fmaxf(x, 0.1f * x); }
__device__ __forceinline__ short f2bf(float x) {   // fp32 -> bf16 RNE (one-time weights)
    unsigned u = __float_as_uint(x);
    return (short)((u + 0x7FFFu + ((u >> 16) & 1u)) >> 16);
}
__device__ __forceinline__ short f2bf_h(float x) { // fp32 -> bf16 round-half-up (per-step)
    return (short)((__float_as_uint(x) + 0x8000u) >> 16);
}
__device__ __forceinline__ float bf2f(short s) {
    return __uint_as_float(((unsigned)(unsigned short)s) << 16);
}
__device__ __forceinline__ short8 ld8bf(const float* __restrict__ p) {
    const float4 a = *(const float4*)p;
    const float4 b = *(const float4*)(p + 4);
    short8 v;
    v[0] = f2bf(a.x); v[1] = f2bf(a.y); v[2] = f2bf(a.z); v[3] = f2bf(a.w);
    v[4] = f2bf(b.x); v[5] = f2bf(b.y); v[6] = f2bf(b.z); v[7] = f2bf(b.w);
    return v;
}
__device__ __forceinline__ short8 ld8bfs(const float* __restrict__ p, float s) {
    const float4 a = *(const float4*)p;
    const float4 b = *(const float4*)(p + 4);
    short8 v;
    v[0] = f2bf(a.x * s); v[1] = f2bf(a.y * s); v[2] = f2bf(a.z * s); v[3] = f2bf(a.w * s);
    v[4] = f2bf(b.x * s); v[5] = f2bf(b.y * s); v[6] = f2bf(b.z * s); v[7] = f2bf(b.w * s);
    return v;
}

// ---------------------------------------------------------------------------
// ONE fused kernel. Block g = scene group g. 512 threads = 8 waves.
//
// R8 change: LDS shrunk 53760 -> 40960 B so 4 blocks/CU fit (grid is exactly
// 4 blocks/CU: 1024/256). Baseline was 3 blocks/CU -> per-CU tail round at
// 8 resident waves, Occupancy 37.7%, VALUBusy 70%. To get there:
//   * Hf SINGLE-buffered (8 KB, was 16 KB dbuf) -> TWO barriers/step
//     (read-drain barrier before in-place write). The dbuf win (R5/R7) was
//     measured at 3 blocks/CU; with a 4th resident block the barrier skew is
//     hidden by other blocks' waves.
//   * persistent sscene dropped: staged transiently in the Hf bytes pre-loop
//     (read into regs before Hf zeroing), re-gathered from L2 post-loop into
//     the spatial union region (scene = 4 MB total, L2-resident, HBM idle).
// launch_bounds(512,8): forces VGPR<=64 (baseline allocates exactly 64; loop
// body keeps the identical per-mt read/compute structure so liveness is flat).
// All arithmetic bit-identical to baseline -> absmax must stay 0.015625.
//
// Phase 1 (GRU): waves 0-3 fwd, 4-7 bwd; wave wd owns gate cols [16wd,16wd+16).
//   B-frags pre-scaled by -1/ln2 (r,z) / 2/ln2 (n); biases added as SCALARS
//   after the MFMA. Gates: sigma(x)=rcp(1+exp2(-x/ln2)),
//   tanh(t)=1-2*rcp(exp2(2t/ln2)+1). Hf write slot permuted
//   (slot = qa*16 + r*4 + quad): 4-way write bank conflicts; reads use
//   permuted lane rlane (bank multiset unchanged).
// Phase 2 (spatial MFMA) + Phase 3 (head): proven R6 structure; spatial
//   arrays overlay dead Xall in a union; Hf region preserved for epilogue.
// ---------------------------------------------------------------------------
__global__ __launch_bounds__(512, 8) void fused_kernel(
    const float* __restrict__ scene, const int* __restrict__ index_div,
    const float* __restrict__ W_emb, const float* __restrict__ b_emb,
    const float* __restrict__ Wih_f, const float* __restrict__ Whh_f,
    const float* __restrict__ bih_f, const float* __restrict__ bhh_f,
    const float* __restrict__ Wih_b, const float* __restrict__ Whh_b,
    const float* __restrict__ bih_b, const float* __restrict__ bhh_b,
    const float* __restrict__ Wm, const float* __restrict__ bm,
    const float* __restrict__ Ws1, const float* __restrict__ bs1,
    const float* __restrict__ Ws2, const float* __restrict__ bs2,
    const float* __restrict__ Wo1, const float* __restrict__ bo1,
    const float* __restrict__ Wo2, const float* __restrict__ bo2,
    float* __restrict__ full_enc, float* __restrict__ out)
{
    __shared__ __align__(16) union SmemU {
        struct {                                     // GRU phase: 40960 B exactly
            short Xall[16 * 2 * 64 * 8];             // [t][mt][lane][8]      32768 B
            short Hf[2 * 2 * 2 * 64 * 8];            // [dir][ks][mt][slot][8] 8192 B (single buf)
        } g;
        struct {                                     // spatial/head phase (25856 B < 32768 B = Xall)
            float su[NGRP][68];                      //  8704 B
            float fe[NGRP][68];                      //  8704 B
            float swo1[1024];                        //  4096 B
            float szero[32];                         //   128 B
            float sscene2[32][33];                   //  4224 B  (re-gathered scene, [c][veh])
        } s;
    } sm;

    const int g    = blockIdx.x;
    const int tid  = threadIdx.x;
    const int lane = tid & 63;
    const int w    = __builtin_amdgcn_readfirstlane(tid >> 6);  // 0..7
    const int dir  = w >> 2;
    const int wd   = w & 3;
    const int cc   = lane & 15;
    const int quad = lane >> 4;
    const int j    = wd * 16 + cc;            // gate column
    const int ks_w = j >> 5;
    const int qa_w = (j >> 3) & 3;
    const int ii_w = j & 7;
    // permuted reader lane: slot(Lq, m) = Lq*16 + (m&3)*4 + (m>>2)
    const int rlane = (lane & 48) | ((lane & 3) << 2) | ((lane >> 2) & 3);

    // ---- stage gathered scene rows into the (not-yet-live) Hf bytes as
    //      float sc0[32][33] (4224 B <= 8192 B). Read back into regs before
    //      Hf is zeroed. ----
    {
        float* sc0 = (float*)sm.g.Hf;
        #pragma unroll
        for (int rep = 0; rep < 2; ++rep) {
            const int idx = tid + rep * 512;
            const int v = idx >> 5, c = idx & 31;
            const int n = index_div[g * NGRP + v];
            sc0[c * 33 + v] = scene[n * 32 + c];
        }
    }

    // ---- per-wave GRU B-frags, pre-scaled; biases stay SCALAR ----
    const float* Wih = dir ? Wih_b : Wih_f;
    const float* Whh = dir ? Whh_b : Whh_f;
    const float* bih = dir ? bih_b : bih_f;
    const float* bhh = dir ? bhh_b : bhh_f;
    const int k0 = quad * 8;
    const float SRZ = -RLN2, SN = 2.0f * RLN2;
    const short8 Br0  = ld8bfs(Whh + (j      ) * 64 + k0,      SRZ);
    const short8 Br1  = ld8bfs(Whh + (j      ) * 64 + 32 + k0, SRZ);
    const short8 Br2  = ld8bfs(Wih + (j      ) * 32 + k0,      SRZ);
    const short8 Bz0  = ld8bfs(Whh + (j +  64) * 64 + k0,      SRZ);
    const short8 Bz1  = ld8bfs(Whh + (j +  64) * 64 + 32 + k0, SRZ);
    const short8 Bz2  = ld8bfs(Wih + (j +  64) * 32 + k0,      SRZ);
    const short8 Bhn0 = ld8bfs(Whh + (j + 128) * 64 + k0,      SN);
    const short8 Bhn1 = ld8bfs(Whh + (j + 128) * 64 + 32 + k0, SN);
    const short8 Bxn  = ld8bfs(Wih + (j + 128) * 32 + k0,      SN);
    const float vb_r  = SRZ * (bih[j] + bhh[j]);
    const float vb_z  = SRZ * (bih[j + 64] + bhh[j + 64]);
    const float vb_xn = SN * bih[j + 128];
    const float vb_hn = SN * bhh[j + 128];

    __syncthreads();   // sc0 ready

    // ---- emb for ALL t (512 threads = 16 t x 32 veh); reads sc0 (in Hf
    //      bytes), writes Xall only. Barrier, THEN zero Hf. ----
    {
        const float* sc0 = (const float*)sm.g.Hf;
        const int t   = tid >> 5;
        const int veh = tid & 31;
        const float xs = sc0[t * 33 + veh];
        const float ys = sc0[(16 + t) * 33 + veh];
        const int mt = veh >> 4;
        const int m  = veh & 15;
        #pragma unroll
        for (int q = 0; q < 4; ++q) {
            short8 v;
            #pragma unroll
            for (int i2 = 0; i2 < 8; ++i2) {
                const int e = q * 8 + i2;
                v[i2] = f2bf(leakyf(fmaf(xs, W_emb[e], fmaf(ys, W_emb[EE + e], b_emb[e]))));
            }
            *(short8*)&sm.g.Xall[(((t * 2 + mt) * 64) + q * 16 + m) * 8] = v;
        }
    }
    __syncthreads();   // all sc0 reads consumed -> Hf bytes reusable
    {
        const short8 z8 = {0, 0, 0, 0, 0, 0, 0, 0};
        *(short8*)&sm.g.Hf[tid * 8] = z8;     // zero all 4096 shorts (both dirs)
    }

    float h_reg[8];
    #pragma unroll
    for (int i = 0; i < 8; ++i) h_reg[i] = 0.0f;

    const int hf_dir = dir * 2048;                 // shorts (dir stride, single buf)
    __syncthreads();   // Hf zeroed

    // ---- GRU main loop: single-buffered Hf, TWO barriers per step ----
    #pragma unroll 2
    for (int s = 0; s < TT; ++s) {
        const int t  = dir ? (TT - 1 - s) : s;
        const short* HfD = &sm.g.Hf[hf_dir];
        #pragma unroll
        for (int mt = 0; mt < 2; ++mt) {
            const short8 Ah0 = *(const short8*)&HfD[((0 * 2 + mt) * 64 + rlane) * 8];
            const short8 Ah1 = *(const short8*)&HfD[((1 * 2 + mt) * 64 + rlane) * 8];
            const short8 Axx = *(const short8*)&sm.g.Xall[((t * 2 + mt) * 64 + lane) * 8];
            const floatx4 z4 = {0.f, 0.f, 0.f, 0.f};
            const floatx4 ar  = MFMA16(Axx, Br2, MFMA16(Ah1, Br1, MFMA16(Ah0, Br0, z4)));
            const floatx4 az  = MFMA16(Axx, Bz2, MFMA16(Ah1, Bz1, MFMA16(Ah0, Bz0, z4)));
            const floatx4 ahn = MFMA16(Ah1, Bhn1, MFMA16(Ah0, Bhn0, z4));
            const floatx4 axn = MFMA16(Axx, Bxn, z4);
            #pragma unroll
            for (int r = 0; r < 4; ++r) {
                // ar = -pre_r/ln2 (pre-scaled); rr = sigmoid(pre_r)
                const float rr = __builtin_amdgcn_rcpf(1.0f + __builtin_amdgcn_exp2f(ar[r] + vb_r));
                const float zz = __builtin_amdgcn_rcpf(1.0f + __builtin_amdgcn_exp2f(az[r] + vb_z));
                // y = 2*(xn + rr*hn)/ln2 ; ng = tanh(xn + rr*hn)
                const float y  = fmaf(rr, ahn[r] + vb_hn, axn[r] + vb_xn);
                const float ng = fmaf(-2.0f,
                                      __builtin_amdgcn_rcpf(__builtin_amdgcn_exp2f(y) + 1.0f),
                                      1.0f);
                const float h0 = h_reg[mt * 4 + r];
                h_reg[mt * 4 + r] = fmaf(zz, h0 - ng, ng);  // (1-z)*ng + z*h
            }
        }
        __syncthreads();   // all waves' Hf reads complete -> in-place write safe
        short* HfW = &sm.g.Hf[hf_dir];
        #pragma unroll
        for (int mt = 0; mt < 2; ++mt) {
            #pragma unroll
            for (int r = 0; r < 4; ++r) {
                const int slot = qa_w * 16 + r * 4 + quad;   // perm of qa*16 + m
                HfW[((ks_w * 2 + mt) * 64 + slot) * 8 + ii_w] = f2bf_h(h_reg[mt * 4 + r]);
            }
        }
        __syncthreads();   // writes visible for next step
    }
    // Final h in Hf[dir]. Xall dead from here.

    // ---- re-gather scene into spatial union region (L2-hot; HBM idle) ----
    #pragma unroll
    for (int rep = 0; rep < 2; ++rep) {
        const int idx = tid + rep * 512;
        const int v = idx >> 5, c = idx & 31;
        const int n = index_div[g * NGRP + v];
        sm.s.sscene2[c][v] = scene[n * 32 + c];
    }
    __syncthreads();   // sscene2 ready

    // ---- Phase 2 prep: waves 0-3 seq_enc epilogue; waves 4-7 su/swo1/szero ----
    if (w < 4) {
        const int nt   = w >> 1;
        const int mt_e = w & 1;
        const int n_col = nt * 16 + cc;
        short8 Bm0, Bm1;
        #pragma unroll
        for (int i = 0; i < 8; ++i) {
            Bm0[i] = f2bf(Wm[(     quad * 8 + i) * 32 + n_col]);
            Bm1[i] = f2bf(Wm[(32 + quad * 8 + i) * 32 + n_col]);
        }
        short8 A0, A1;
        #pragma unroll
        for (int ks = 0; ks < 2; ++ks) {
            const short8 F = *(const short8*)&sm.g.Hf[0    + ((ks * 2 + mt_e) * 64 + rlane) * 8];
            const short8 B = *(const short8*)&sm.g.Hf[2048 + ((ks * 2 + mt_e) * 64 + rlane) * 8];
            #pragma unroll
            for (int i = 0; i < 8; ++i) {
                const short v = f2bf(0.5f * (bf2f(F[i]) + bf2f(B[i])));
                if (ks == 0) A0[i] = v; else A1[i] = v;
            }
        }
        const floatx4 z4 = {0.f, 0.f, 0.f, 0.f};
        const floatx4 acc = MFMA16(A1, Bm1, MFMA16(A0, Bm0, z4));
        const float bmn = bm[n_col];
        #pragma unroll
        for (int r = 0; r < 4; ++r) {
            const int veh = mt_e * 16 + quad * 4 + r;
            const float sv = leakyf(acc[r] + bmn);
            const int n = index_div[g * NGRP + veh];
            full_enc[n * HH + n_col] = sv;
            sm.s.fe[veh][n_col] = sv;     // fe region does not overlap Hf
        }
    } else {
        const int l  = tid & 255;
        const int v  = l >> 3;
        const int d0 = (l & 7) * 8;
        float acc[8];
        #pragma unroll
        for (int i = 0; i < 8; ++i) acc[i] = 0.0f;
        #pragma unroll
        for (int e = 0; e < EE; ++e) {
            const float f = sm.s.sscene2[e][v];
            const float4 w0 = *(const float4*)&Ws1[e * 64 + d0];
            const float4 w1 = *(const float4*)&Ws1[e * 64 + d0 + 4];
            acc[0] = fmaf(f, w0.x, acc[0]); acc[1] = fmaf(f, w0.y, acc[1]);
            acc[2] = fmaf(f, w0.z, acc[2]); acc[3] = fmaf(f, w0.w, acc[3]);
            acc[4] = fmaf(f, w1.x, acc[4]); acc[5] = fmaf(f, w1.y, acc[5]);
            acc[6] = fmaf(f, w1.z, acc[6]); acc[7] = fmaf(f, w1.w, acc[7]);
        }
        #pragma unroll
        for (int i = 0; i < 8; ++i) sm.s.su[v][d0 + i] = acc[i];
        *(float4*)&sm.s.swo1[l * 4] = *(const float4*)&Wo1[l * 4];
        if (l < 32) {
            float zs = bs2[l];
            #pragma unroll
            for (int d = 0; d < HH; ++d) zs = fmaf(leakyf(bs1[d]), Ws2[d * 32 + l], zs);
            sm.s.szero[l] = leakyf(zs);
        }
    }

    // ---- spatial B-frags (all 8 waves) ----
    short8 Bw00, Bw01, Bw10, Bw11;
    #pragma unroll
    for (int i = 0; i < 8; ++i) {
        Bw00[i] = f2bf(Ws2[(     quad * 8 + i) * 32 + cc]);
        Bw01[i] = f2bf(Ws2[(32 + quad * 8 + i) * 32 + cc]);
        Bw10[i] = f2bf(Ws2[(     quad * 8 + i) * 32 + 16 + cc]);
        Bw11[i] = f2bf(Ws2[(32 + quad * 8 + i) * 32 + 16 + cc]);
    }
    float bsq0[8], bsq1[8];
    #pragma unroll
    for (int i = 0; i < 8; ++i) {
        bsq0[i] = bs1[quad * 8 + i];
        bsq1[i] = bs1[32 + quad * 8 + i];
    }
    const float bs2c0 = bs2[cc], bs2c1 = bs2[16 + cc];
    __syncthreads();

    // ---- spatial pairwise MLP: 8 waves x 4 j's ----
    #pragma unroll 2
    for (int jj = 0; jj < 4; ++jj) {
        const int jrow = w * 4 + jj;       // wave-uniform j, 0..31
        float vj0[8], vj1[8];
        #pragma unroll
        for (int i = 0; i < 8; ++i) {
            vj0[i] = sm.s.su[jrow][quad * 8 + i] - bsq0[i];
            vj1[i] = sm.s.su[jrow][32 + quad * 8 + i] - bsq1[i];
        }
        float acc0 = 0.0f, acc1 = 0.0f;
        #pragma unroll
        for (int it = 0; it < 2; ++it) {
            const int irow = it * 16 + cc;   // A-frag row m = cc
            const float4 p0 = *(const float4*)&sm.s.su[irow][quad * 8];
            const float4 p1 = *(const float4*)&sm.s.su[irow][quad * 8 + 4];
            const float4 p2 = *(const float4*)&sm.s.su[irow][32 + quad * 8];
            const float4 p3 = *(const float4*)&sm.s.su[irow][32 + quad * 8 + 4];
            short8 A0, A1;
            A0[0] = f2bf(leakyf(p0.x - vj0[0])); A0[1] = f2bf(leakyf(p0.y - vj0[1]));
            A0[2] = f2bf(leakyf(p0.z - vj0[2])); A0[3] = f2bf(leakyf(p0.w - vj0[3]));
            A0[4] = f2bf(leakyf(p1.x - vj0[4])); A0[5] = f2bf(leakyf(p1.y - vj0[5]));
            A0[6] = f2bf(leakyf(p1.z - vj0[6])); A0[7] = f2bf(leakyf(p1.w - vj0[7]));
            A1[0] = f2bf(leakyf(p2.x - vj1[0])); A1[1] = f2bf(leakyf(p2.y - vj1[1]));
            A1[2] = f2bf(leakyf(p2.z - vj1[2])); A1[3] = f2bf(leakyf(p2.w - vj1[3]));
            A1[4] = f2bf(leakyf(p3.x - vj1[4])); A1[5] = f2bf(leakyf(p3.y - vj1[5]));
            A1[6] = f2bf(leakyf(p3.z - vj1[6])); A1[7] = f2bf(leakyf(p3.w - vj1[7]));
            const floatx4 z4 = {0.f, 0.f, 0.f, 0.f};
            const floatx4 D0 = MFMA16(A1, Bw01, MFMA16(A0, Bw00, z4));
            const floatx4 D1 = MFMA16(A1, Bw11, MFMA16(A0, Bw10, z4));
            #pragma unroll
            for (int r = 0; r < 4; ++r) {
                acc0 += leakyf(D0[r] + bs2c0);
                acc1 += leakyf(D1[r] + bs2c1);
            }
        }
        acc0 += __shfl_xor(acc0, 16, 64); acc0 += __shfl_xor(acc0, 32, 64);
        acc1 += __shfl_xor(acc1, 16, 64); acc1 += __shfl_xor(acc1, 32, 64);
        const int n = index_div[g * NGRP + jrow];
        if (quad == 0) {
            const float pv = (acc0 - sm.s.szero[cc]) * (1.0f / 31.0f);
            full_enc[n * HH + 32 + cc] = pv;
            sm.s.fe[jrow][32 + cc] = pv;
        } else if (quad == 1) {
            const float pv = (acc1 - sm.s.szero[16 + cc]) * (1.0f / 31.0f);
            full_enc[n * HH + 48 + cc] = pv;
            sm.s.fe[jrow][48 + cc] = pv;
        }
    }
    __syncthreads();

    // ---- head: x_logit = leaky(fe @ Wo1 + bo1) @ Wo2 + bo2 ----
    {
        const int veh = tid >> 4;          // 0..31
        const int p   = tid & 15;          // hidden dim
        float a = bo1[p];
        #pragma unroll
        for (int k = 0; k < HH; ++k)
            a = fmaf(sm.s.fe[veh][k], sm.s.swo1[k * 16 + p], a);
        a = leakyf(a);
        float l0 = a * Wo2[p * 3 + 0];
        float l1 = a * Wo2[p * 3 + 1];
        float l2 = a * Wo2[p * 3 + 2];
        #pragma unroll
        for (int off = 1; off < 16; off <<= 1) {
            l0 += __shfl_xor(l0, off, 64);
            l1 += __shfl_xor(l1, off, 64);
            l2 += __shfl_xor(l2, off, 64);
        }
        if (p == 0) {
            const int n = index_div[g * NGRP + veh];
            out[n * 3 + 0] = l0 + bo2[0];
            out[n * 3 + 1] = l1 + bo2[1];
            out[n * 3 + 2] = l2 + bo2[2];
        }
    }
}

// ---------------------------------------------------------------------------
extern "C" void kernel_launch(void* const* d_in, const int* in_sizes, int n_in,
                              void* d_out, int out_size, void* d_ws, size_t ws_size,
                              hipStream_t stream) {
    const float* scene     = (const float*)d_in[0];
    const int*   index_div = (const int*)d_in[4];
    const float* W_emb = (const float*)d_in[5];
    const float* b_emb = (const float*)d_in[6];
    const float* Wih_f = (const float*)d_in[7];
    const float* Whh_f = (const float*)d_in[8];
    const float* bih_f = (const float*)d_in[9];
    const float* bhh_f = (const float*)d_in[10];
    const float* Wih_b = (const float*)d_in[11];
    const float* Whh_b = (const float*)d_in[12];
    const float* bih_b = (const float*)d_in[13];
    const float* bhh_b = (const float*)d_in[14];
    const float* Wm  = (const float*)d_in[15];
    const float* bm  = (const float*)d_in[16];
    const float* Ws1 = (const float*)d_in[17];
    const float* bs1 = (const float*)d_in[18];
    const float* Ws2 = (const float*)d_in[19];
    const float* bs2 = (const float*)d_in[20];
    const float* Wo1 = (const float*)d_in[21];
    const float* bo1 = (const float*)d_in[22];
    const float* Wo2 = (const float*)d_in[23];
    const float* bo2 = (const float*)d_in[24];

    const int N = in_sizes[0] / (2 * TT);   // 32768
    const int G = in_sizes[4] / NGRP;       // 1024

    float* out      = (float*)d_out;
    float* full_enc = out + (size_t)N * CC;

    fused_kernel<<<dim3(G), dim3(512), 0, stream>>>(
        scene, index_div, W_emb, b_emb, Wih_f, Whh_f, bih_f, bhh_f,
        Wih_b, Whh_b, bih_b, bhh_b, Wm, bm, Ws1, bs1, Ws2, bs2,
        Wo1, bo1, Wo2, bo2, full_enc, out);
}

// Round 2
// 194.747 us; speedup vs baseline: 2.3262x; 2.3262x over previous
//
#include <hip/hip_runtime.h>
#include <hip/hip_bf16.h>

#define TT 16      // in_length
#define EE 32      // embedding size
#define HH 64      // encoder size
#define NGRP 32    // vehicles per group
#define CC 3       // classes

typedef __attribute__((ext_vector_type(8))) short short8;
typedef __attribute__((ext_vector_type(4))) float floatx4;

#define MFMA16(a, b, c) __builtin_amdgcn_mfma_f32_16x16x32_bf16((a), (b), (c), 0, 0, 0)

#define RLN2 1.4426950408889634f   // 1/ln2

__device__ __forceinline__ float leakyf(float x) { return fmaxf(x, 0.1f * x); }
__device__ __forceinline__ short f2bf(float x) {   // fp32 -> bf16 RNE (one-time weights)
    unsigned u = __float_as_uint(x);
    return (short)((u + 0x7FFFu + ((u >> 16) & 1u)) >> 16);
}
__device__ __forceinline__ short f2bf_h(float x) { // fp32 -> bf16 round-half-up (per-step)
    return (short)((__float_as_uint(x) + 0x8000u) >> 16);
}
__device__ __forceinline__ float bf2f(short s) {
    return __uint_as_float(((unsigned)(unsigned short)s) << 16);
}
__device__ __forceinline__ short8 ld8bf(const float* __restrict__ p) {
    const float4 a = *(const float4*)p;
    const float4 b = *(const float4*)(p + 4);
    short8 v;
    v[0] = f2bf(a.x); v[1] = f2bf(a.y); v[2] = f2bf(a.z); v[3] = f2bf(a.w);
    v[4] = f2bf(b.x); v[5] = f2bf(b.y); v[6] = f2bf(b.z); v[7] = f2bf(b.w);
    return v;
}
__device__ __forceinline__ short8 ld8bfs(const float* __restrict__ p, float s) {
    const float4 a = *(const float4*)p;
    const float4 b = *(const float4*)(p + 4);
    short8 v;
    v[0] = f2bf(a.x * s); v[1] = f2bf(a.y * s); v[2] = f2bf(a.z * s); v[3] = f2bf(a.w * s);
    v[4] = f2bf(b.x * s); v[5] = f2bf(b.y * s); v[6] = f2bf(b.z * s); v[7] = f2bf(b.w * s);
    return v;
}

// ---------------------------------------------------------------------------
// ONE fused kernel. Block g = scene group g. 512 threads = 8 waves.
//
// R9: R8's LDS diet (53760 -> 40960 B, 4 blocks/CU; CONFIRMED: Occupancy hit
// 83%) kept, but launch_bounds reverted (512,8) -> (512,4). The (512,8) cap
// squeezed the unified VGPR/AGPR budget to 64 total/lane (VGPR_Count=32) and
// spilled the 9 loop-live B-frags: FETCH_SIZE 2.98 MB -> 880 MB, 46% HBM,
// VALUBusy 20%. (512,4) is the baseline-proven 64-VGPR no-spill cap; HW
// occupancy = min(LDS 4 blocks, VGPR<=64 -> 8 waves/SIMD) = 4 blocks/CU.
// Sentinel: VGPR_Count > 64 in counters => occupancy halves, revert layout.
//
// LDS layout (40960 B):
//   * Hf SINGLE-buffered (8 KB, was 16 KB dbuf) -> TWO barriers/step
//     (read-drain barrier before in-place write).
//   * persistent sscene dropped: staged transiently in the Hf bytes pre-loop,
//     re-gathered from L2 post-loop into the spatial union region.
//
// Phase 1 (GRU): waves 0-3 fwd, 4-7 bwd; wave wd owns gate cols [16wd,16wd+16).
//   B-frags pre-scaled by -1/ln2 (r,z) / 2/ln2 (n); biases added as SCALARS
//   after the MFMA. Gates: sigma(x)=rcp(1+exp2(-x/ln2)),
//   tanh(t)=1-2*rcp(exp2(2t/ln2)+1). Hf write slot permuted
//   (slot = qa*16 + r*4 + quad): 4-way write bank conflicts; reads use
//   permuted lane rlane (bank multiset unchanged).
// Phase 2 (spatial MFMA) + Phase 3 (head): proven R6 structure; spatial
//   arrays overlay dead Xall in a union; Hf region preserved for epilogue.
// ---------------------------------------------------------------------------
__global__ __launch_bounds__(512, 4) void fused_kernel(
    const float* __restrict__ scene, const int* __restrict__ index_div,
    const float* __restrict__ W_emb, const float* __restrict__ b_emb,
    const float* __restrict__ Wih_f, const float* __restrict__ Whh_f,
    const float* __restrict__ bih_f, const float* __restrict__ bhh_f,
    const float* __restrict__ Wih_b, const float* __restrict__ Whh_b,
    const float* __restrict__ bih_b, const float* __restrict__ bhh_b,
    const float* __restrict__ Wm, const float* __restrict__ bm,
    const float* __restrict__ Ws1, const float* __restrict__ bs1,
    const float* __restrict__ Ws2, const float* __restrict__ bs2,
    const float* __restrict__ Wo1, const float* __restrict__ bo1,
    const float* __restrict__ Wo2, const float* __restrict__ bo2,
    float* __restrict__ full_enc, float* __restrict__ out)
{
    __shared__ __align__(16) union SmemU {
        struct {                                     // GRU phase: 40960 B exactly
            short Xall[16 * 2 * 64 * 8];             // [t][mt][lane][8]      32768 B
            short Hf[2 * 2 * 2 * 64 * 8];            // [dir][ks][mt][slot][8] 8192 B (single buf)
        } g;
        struct {                                     // spatial/head phase (25856 B < 32768 B = Xall)
            float su[NGRP][68];                      //  8704 B
            float fe[NGRP][68];                      //  8704 B
            float swo1[1024];                        //  4096 B
            float szero[32];                         //   128 B
            float sscene2[32][33];                   //  4224 B  (re-gathered scene, [c][veh])
        } s;
    } sm;

    const int g    = blockIdx.x;
    const int tid  = threadIdx.x;
    const int lane = tid & 63;
    const int w    = __builtin_amdgcn_readfirstlane(tid >> 6);  // 0..7
    const int dir  = w >> 2;
    const int wd   = w & 3;
    const int cc   = lane & 15;
    const int quad = lane >> 4;
    const int j    = wd * 16 + cc;            // gate column
    const int ks_w = j >> 5;
    const int qa_w = (j >> 3) & 3;
    const int ii_w = j & 7;
    // permuted reader lane: slot(Lq, m) = Lq*16 + (m&3)*4 + (m>>2)
    const int rlane = (lane & 48) | ((lane & 3) << 2) | ((lane >> 2) & 3);

    // ---- stage gathered scene rows into the (not-yet-live) Hf bytes as
    //      float sc0[32][33] (4224 B <= 8192 B). Read back into regs before
    //      Hf is zeroed. ----
    {
        float* sc0 = (float*)sm.g.Hf;
        #pragma unroll
        for (int rep = 0; rep < 2; ++rep) {
            const int idx = tid + rep * 512;
            const int v = idx >> 5, c = idx & 31;
            const int n = index_div[g * NGRP + v];
            sc0[c * 33 + v] = scene[n * 32 + c];
        }
    }

    // ---- per-wave GRU B-frags, pre-scaled; biases stay SCALAR ----
    const float* Wih = dir ? Wih_b : Wih_f;
    const float* Whh = dir ? Whh_b : Whh_f;
    const float* bih = dir ? bih_b : bih_f;
    const float* bhh = dir ? bhh_b : bhh_f;
    const int k0 = quad * 8;
    const float SRZ = -RLN2, SN = 2.0f * RLN2;
    const short8 Br0  = ld8bfs(Whh + (j      ) * 64 + k0,      SRZ);
    const short8 Br1  = ld8bfs(Whh + (j      ) * 64 + 32 + k0, SRZ);
    const short8 Br2  = ld8bfs(Wih + (j      ) * 32 + k0,      SRZ);
    const short8 Bz0  = ld8bfs(Whh + (j +  64) * 64 + k0,      SRZ);
    const short8 Bz1  = ld8bfs(Whh + (j +  64) * 64 + 32 + k0, SRZ);
    const short8 Bz2  = ld8bfs(Wih + (j +  64) * 32 + k0,      SRZ);
    const short8 Bhn0 = ld8bfs(Whh + (j + 128) * 64 + k0,      SN);
    const short8 Bhn1 = ld8bfs(Whh + (j + 128) * 64 + 32 + k0, SN);
    const short8 Bxn  = ld8bfs(Wih + (j + 128) * 32 + k0,      SN);
    const float vb_r  = SRZ * (bih[j] + bhh[j]);
    const float vb_z  = SRZ * (bih[j + 64] + bhh[j + 64]);
    const float vb_xn = SN * bih[j + 128];
    const float vb_hn = SN * bhh[j + 128];

    __syncthreads();   // sc0 ready

    // ---- emb for ALL t (512 threads = 16 t x 32 veh); reads sc0 (in Hf
    //      bytes), writes Xall only. Barrier, THEN zero Hf. ----
    {
        const float* sc0 = (const float*)sm.g.Hf;
        const int t   = tid >> 5;
        const int veh = tid & 31;
        const float xs = sc0[t * 33 + veh];
        const float ys = sc0[(16 + t) * 33 + veh];
        const int mt = veh >> 4;
        const int m  = veh & 15;
        #pragma unroll
        for (int q = 0; q < 4; ++q) {
            short8 v;
            #pragma unroll
            for (int i2 = 0; i2 < 8; ++i2) {
                const int e = q * 8 + i2;
                v[i2] = f2bf(leakyf(fmaf(xs, W_emb[e], fmaf(ys, W_emb[EE + e], b_emb[e]))));
            }
            *(short8*)&sm.g.Xall[(((t * 2 + mt) * 64) + q * 16 + m) * 8] = v;
        }
    }
    __syncthreads();   // all sc0 reads consumed -> Hf bytes reusable
    {
        const short8 z8 = {0, 0, 0, 0, 0, 0, 0, 0};
        *(short8*)&sm.g.Hf[tid * 8] = z8;     // zero all 4096 shorts (both dirs)
    }

    float h_reg[8];
    #pragma unroll
    for (int i = 0; i < 8; ++i) h_reg[i] = 0.0f;

    const int hf_dir = dir * 2048;                 // shorts (dir stride, single buf)
    __syncthreads();   // Hf zeroed

    // ---- GRU main loop: single-buffered Hf, TWO barriers per step ----
    #pragma unroll 2
    for (int s = 0; s < TT; ++s) {
        const int t  = dir ? (TT - 1 - s) : s;
        const short* HfD = &sm.g.Hf[hf_dir];
        #pragma unroll
        for (int mt = 0; mt < 2; ++mt) {
            const short8 Ah0 = *(const short8*)&HfD[((0 * 2 + mt) * 64 + rlane) * 8];
            const short8 Ah1 = *(const short8*)&HfD[((1 * 2 + mt) * 64 + rlane) * 8];
            const short8 Axx = *(const short8*)&sm.g.Xall[((t * 2 + mt) * 64 + lane) * 8];
            const floatx4 z4 = {0.f, 0.f, 0.f, 0.f};
            const floatx4 ar  = MFMA16(Axx, Br2, MFMA16(Ah1, Br1, MFMA16(Ah0, Br0, z4)));
            const floatx4 az  = MFMA16(Axx, Bz2, MFMA16(Ah1, Bz1, MFMA16(Ah0, Bz0, z4)));
            const floatx4 ahn = MFMA16(Ah1, Bhn1, MFMA16(Ah0, Bhn0, z4));
            const floatx4 axn = MFMA16(Axx, Bxn, z4);
            #pragma unroll
            for (int r = 0; r < 4; ++r) {
                // ar = -pre_r/ln2 (pre-scaled); rr = sigmoid(pre_r)
                const float rr = __builtin_amdgcn_rcpf(1.0f + __builtin_amdgcn_exp2f(ar[r] + vb_r));
                const float zz = __builtin_amdgcn_rcpf(1.0f + __builtin_amdgcn_exp2f(az[r] + vb_z));
                // y = 2*(xn + rr*hn)/ln2 ; ng = tanh(xn + rr*hn)
                const float y  = fmaf(rr, ahn[r] + vb_hn, axn[r] + vb_xn);
                const float ng = fmaf(-2.0f,
                                      __builtin_amdgcn_rcpf(__builtin_amdgcn_exp2f(y) + 1.0f),
                                      1.0f);
                const float h0 = h_reg[mt * 4 + r];
                h_reg[mt * 4 + r] = fmaf(zz, h0 - ng, ng);  // (1-z)*ng + z*h
            }
        }
        __syncthreads();   // all waves' Hf reads complete -> in-place write safe
        short* HfW = &sm.g.Hf[hf_dir];
        #pragma unroll
        for (int mt = 0; mt < 2; ++mt) {
            #pragma unroll
            for (int r = 0; r < 4; ++r) {
                const int slot = qa_w * 16 + r * 4 + quad;   // perm of qa*16 + m
                HfW[((ks_w * 2 + mt) * 64 + slot) * 8 + ii_w] = f2bf_h(h_reg[mt * 4 + r]);
            }
        }
        __syncthreads();   // writes visible for next step
    }
    // Final h in Hf[dir]. Xall dead from here.

    // ---- re-gather scene into spatial union region (L2-hot; HBM idle) ----
    #pragma unroll
    for (int rep = 0; rep < 2; ++rep) {
        const int idx = tid + rep * 512;
        const int v = idx >> 5, c = idx & 31;
        const int n = index_div[g * NGRP + v];
        sm.s.sscene2[c][v] = scene[n * 32 + c];
    }
    __syncthreads();   // sscene2 ready

    // ---- Phase 2 prep: waves 0-3 seq_enc epilogue; waves 4-7 su/swo1/szero ----
    if (w < 4) {
        const int nt   = w >> 1;
        const int mt_e = w & 1;
        const int n_col = nt * 16 + cc;
        short8 Bm0, Bm1;
        #pragma unroll
        for (int i = 0; i < 8; ++i) {
            Bm0[i] = f2bf(Wm[(     quad * 8 + i) * 32 + n_col]);
            Bm1[i] = f2bf(Wm[(32 + quad * 8 + i) * 32 + n_col]);
        }
        short8 A0, A1;
        #pragma unroll
        for (int ks = 0; ks < 2; ++ks) {
            const short8 F = *(const short8*)&sm.g.Hf[0    + ((ks * 2 + mt_e) * 64 + rlane) * 8];
            const short8 B = *(const short8*)&sm.g.Hf[2048 + ((ks * 2 + mt_e) * 64 + rlane) * 8];
            #pragma unroll
            for (int i = 0; i < 8; ++i) {
                const short v = f2bf(0.5f * (bf2f(F[i]) + bf2f(B[i])));
                if (ks == 0) A0[i] = v; else A1[i] = v;
            }
        }
        const floatx4 z4 = {0.f, 0.f, 0.f, 0.f};
        const floatx4 acc = MFMA16(A1, Bm1, MFMA16(A0, Bm0, z4));
        const float bmn = bm[n_col];
        #pragma unroll
        for (int r = 0; r < 4; ++r) {
            const int veh = mt_e * 16 + quad * 4 + r;
            const float sv = leakyf(acc[r] + bmn);
            const int n = index_div[g * NGRP + veh];
            full_enc[n * HH + n_col] = sv;
            sm.s.fe[veh][n_col] = sv;     // fe region does not overlap Hf
        }
    } else {
        const int l  = tid & 255;
        const int v  = l >> 3;
        const int d0 = (l & 7) * 8;
        float acc[8];
        #pragma unroll
        for (int i = 0; i < 8; ++i) acc[i] = 0.0f;
        #pragma unroll
        for (int e = 0; e < EE; ++e) {
            const float f = sm.s.sscene2[e][v];
            const float4 w0 = *(const float4*)&Ws1[e * 64 + d0];
            const float4 w1 = *(const float4*)&Ws1[e * 64 + d0 + 4];
            acc[0] = fmaf(f, w0.x, acc[0]); acc[1] = fmaf(f, w0.y, acc[1]);
            acc[2] = fmaf(f, w0.z, acc[2]); acc[3] = fmaf(f, w0.w, acc[3]);
            acc[4] = fmaf(f, w1.x, acc[4]); acc[5] = fmaf(f, w1.y, acc[5]);
            acc[6] = fmaf(f, w1.z, acc[6]); acc[7] = fmaf(f, w1.w, acc[7]);
        }
        #pragma unroll
        for (int i = 0; i < 8; ++i) sm.s.su[v][d0 + i] = acc[i];
        *(float4*)&sm.s.swo1[l * 4] = *(const float4*)&Wo1[l * 4];
        if (l < 32) {
            float zs = bs2[l];
            #pragma unroll
            for (int d = 0; d < HH; ++d) zs = fmaf(leakyf(bs1[d]), Ws2[d * 32 + l], zs);
            sm.s.szero[l] = leakyf(zs);
        }
    }

    // ---- spatial B-frags (all 8 waves) ----
    short8 Bw00, Bw01, Bw10, Bw11;
    #pragma unroll
    for (int i = 0; i < 8; ++i) {
        Bw00[i] = f2bf(Ws2[(     quad * 8 + i) * 32 + cc]);
        Bw01[i] = f2bf(Ws2[(32 + quad * 8 + i) * 32 + cc]);
        Bw10[i] = f2bf(Ws2[(     quad * 8 + i) * 32 + 16 + cc]);
        Bw11[i] = f2bf(Ws2[(32 + quad * 8 + i) * 32 + 16 + cc]);
    }
    float bsq0[8], bsq1[8];
    #pragma unroll
    for (int i = 0; i < 8; ++i) {
        bsq0[i] = bs1[quad * 8 + i];
        bsq1[i] = bs1[32 + quad * 8 + i];
    }
    const float bs2c0 = bs2[cc], bs2c1 = bs2[16 + cc];
    __syncthreads();

    // ---- spatial pairwise MLP: 8 waves x 4 j's ----
    #pragma unroll 2
    for (int jj = 0; jj < 4; ++jj) {
        const int jrow = w * 4 + jj;       // wave-uniform j, 0..31
        float vj0[8], vj1[8];
        #pragma unroll
        for (int i = 0; i < 8; ++i) {
            vj0[i] = sm.s.su[jrow][quad * 8 + i] - bsq0[i];
            vj1[i] = sm.s.su[jrow][32 + quad * 8 + i] - bsq1[i];
        }
        float acc0 = 0.0f, acc1 = 0.0f;
        #pragma unroll
        for (int it = 0; it < 2; ++it) {
            const int irow = it * 16 + cc;   // A-frag row m = cc
            const float4 p0 = *(const float4*)&sm.s.su[irow][quad * 8];
            const float4 p1 = *(const float4*)&sm.s.su[irow][quad * 8 + 4];
            const float4 p2 = *(const float4*)&sm.s.su[irow][32 + quad * 8];
            const float4 p3 = *(const float4*)&sm.s.su[irow][32 + quad * 8 + 4];
            short8 A0, A1;
            A0[0] = f2bf(leakyf(p0.x - vj0[0])); A0[1] = f2bf(leakyf(p0.y - vj0[1]));
            A0[2] = f2bf(leakyf(p0.z - vj0[2])); A0[3] = f2bf(leakyf(p0.w - vj0[3]));
            A0[4] = f2bf(leakyf(p1.x - vj0[4])); A0[5] = f2bf(leakyf(p1.y - vj0[5]));
            A0[6] = f2bf(leakyf(p1.z - vj0[6])); A0[7] = f2bf(leakyf(p1.w - vj0[7]));
            A1[0] = f2bf(leakyf(p2.x - vj1[0])); A1[1] = f2bf(leakyf(p2.y - vj1[1]));
            A1[2] = f2bf(leakyf(p2.z - vj1[2])); A1[3] = f2bf(leakyf(p2.w - vj1[3]));
            A1[4] = f2bf(leakyf(p3.x - vj1[4])); A1[5] = f2bf(leakyf(p3.y - vj1[5]));
            A1[6] = f2bf(leakyf(p3.z - vj1[6])); A1[7] = f2bf(leakyf(p3.w - vj1[7]));
            const floatx4 z4 = {0.f, 0.f, 0.f, 0.f};
            const floatx4 D0 = MFMA16(A1, Bw01, MFMA16(A0, Bw00, z4));
            const floatx4 D1 = MFMA16(A1, Bw11, MFMA16(A0, Bw10, z4));
            #pragma unroll
            for (int r = 0; r < 4; ++r) {
                acc0 += leakyf(D0[r] + bs2c0);
                acc1 += leakyf(D1[r] + bs2c1);
            }
        }
        acc0 += __shfl_xor(acc0, 16, 64); acc0 += __shfl_xor(acc0, 32, 64);
        acc1 += __shfl_xor(acc1, 16, 64); acc1 += __shfl_xor(acc1, 32, 64);
        const int n = index_div[g * NGRP + jrow];
        if (quad == 0) {
            const float pv = (acc0 - sm.s.szero[cc]) * (1.0f / 31.0f);
            full_enc[n * HH + 32 + cc] = pv;
            sm.s.fe[jrow][32 + cc] = pv;
        } else if (quad == 1) {
            const float pv = (acc1 - sm.s.szero[16 + cc]) * (1.0f / 31.0f);
            full_enc[n * HH + 48 + cc] = pv;
            sm.s.fe[jrow][48 + cc] = pv;
        }
    }
    __syncthreads();

    // ---- head: x_logit = leaky(fe @ Wo1 + bo1) @ Wo2 + bo2 ----
    {
        const int veh = tid >> 4;          // 0..31
        const int p   = tid & 15;          // hidden dim
        float a = bo1[p];
        #pragma unroll
        for (int k = 0; k < HH; ++k)
            a = fmaf(sm.s.fe[veh][k], sm.s.swo1[k * 16 + p], a);
        a = leakyf(a);
        float l0 = a * Wo2[p * 3 + 0];
        float l1 = a * Wo2[p * 3 + 1];
        float l2 = a * Wo2[p * 3 + 2];
        #pragma unroll
        for (int off = 1; off < 16; off <<= 1) {
            l0 += __shfl_xor(l0, off, 64);
            l1 += __shfl_xor(l1, off, 64);
            l2 += __shfl_xor(l2, off, 64);
        }
        if (p == 0) {
            const int n = index_div[g * NGRP + veh];
            out[n * 3 + 0] = l0 + bo2[0];
            out[n * 3 + 1] = l1 + bo2[1];
            out[n * 3 + 2] = l2 + bo2[2];
        }
    }
}

// ---------------------------------------------------------------------------
extern "C" void kernel_launch(void* const* d_in, const int* in_sizes, int n_in,
                              void* d_out, int out_size, void* d_ws, size_t ws_size,
                              hipStream_t stream) {
    const float* scene     = (const float*)d_in[0];
    const int*   index_div = (const int*)d_in[4];
    const float* W_emb = (const float*)d_in[5];
    const float* b_emb = (const float*)d_in[6];
    const float* Wih_f = (const float*)d_in[7];
    const float* Whh_f = (const float*)d_in[8];
    const float* bih_f = (const float*)d_in[9];
    const float* bhh_f = (const float*)d_in[10];
    const float* Wih_b = (const float*)d_in[11];
    const float* Whh_b = (const float*)d_in[12];
    const float* bih_b = (const float*)d_in[13];
    const float* bhh_b = (const float*)d_in[14];
    const float* Wm  = (const float*)d_in[15];
    const float* bm  = (const float*)d_in[16];
    const float* Ws1 = (const float*)d_in[17];
    const float* bs1 = (const float*)d_in[18];
    const float* Ws2 = (const float*)d_in[19];
    const float* bs2 = (const float*)d_in[20];
    const float* Wo1 = (const float*)d_in[21];
    const float* bo1 = (const float*)d_in[22];
    const float* Wo2 = (const float*)d_in[23];
    const float* bo2 = (const float*)d_in[24];

    const int N = in_sizes[0] / (2 * TT);   // 32768
    const int G = in_sizes[4] / NGRP;       // 1024

    float* out      = (float*)d_out;
    float* full_enc = out + (size_t)N * CC;

    fused_kernel<<<dim3(G), dim3(512), 0, stream>>>(
        scene, index_div, W_emb, b_emb, Wih_f, Whh_f, bih_f, bhh_f,
        Wih_b, Whh_b, bih_b, bhh_b, Wm, bm, Ws1, bs1, Ws2, bs2,
        Wo1, bo1, Wo2, bo2, full_enc, out);
}

// Round 3
// 194.190 us; speedup vs baseline: 2.3329x; 1.0029x over previous
//
#include <hip/hip_runtime.h>
#include <hip/hip_bf16.h>

#define TT 16      // in_length
#define EE 32      // embedding size
#define HH 64      // encoder size
#define NGRP 32    // vehicles per group
#define CC 3       // classes

typedef __attribute__((ext_vector_type(8))) short short8;
typedef __attribute__((ext_vector_type(4))) float floatx4;
typedef __attribute__((ext_vector_type(2))) float float2v;
typedef __attribute__((ext_vector_type(4))) unsigned uint4v;

#define MFMA16(a, b, c) __builtin_amdgcn_mfma_f32_16x16x32_bf16((a), (b), (c), 0, 0, 0)

#define RLN2 1.4426950408889634f   // 1/ln2

__device__ __forceinline__ float leakyf(float x) { return fmaxf(x, 0.1f * x); }
__device__ __forceinline__ float2v mk2(float a, float b) { float2v v; v.x = a; v.y = b; return v; }
__device__ __forceinline__ float2v leaky2(float2v x) {      // v_pk_mul + v_pk_max
    return __builtin_elementwise_max(x, x * 0.1f);
}
__device__ __forceinline__ short f2bf(float x) {   // fp32 -> bf16 RNE (one-time weights)
    unsigned u = __float_as_uint(x);
    return (short)((u + 0x7FFFu + ((u >> 16) & 1u)) >> 16);
}
__device__ __forceinline__ short f2bf_h(float x) { // fp32 -> bf16 round-half-up (per-step)
    return (short)((__float_as_uint(x) + 0x8000u) >> 16);
}
__device__ __forceinline__ float bf2f(short s) {
    return __uint_as_float(((unsigned)(unsigned short)s) << 16);
}
// ONE instruction for 2 fp32->bf16 RNE (bitwise == f2bf on normal values).
// Non-volatile, reg-only asm: scheduler may move it freely (m240 pin risk avoided).
__device__ __forceinline__ unsigned cvtpk(float lo, float hi) {
    unsigned r;
    asm("v_cvt_pk_bf16_f32 %0, %1, %2" : "=v"(r) : "v"(lo), "v"(hi));
    return r;
}
__device__ __forceinline__ unsigned cvtpk2(float2v l) { return cvtpk(l.x, l.y); }

__device__ __forceinline__ short8 ld8bfs(const float* __restrict__ p, float s) {
    const float4 a = *(const float4*)p;
    const float4 b = *(const float4*)(p + 4);
    short8 v;
    v[0] = f2bf(a.x * s); v[1] = f2bf(a.y * s); v[2] = f2bf(a.z * s); v[3] = f2bf(a.w * s);
    v[4] = f2bf(b.x * s); v[5] = f2bf(b.y * s); v[6] = f2bf(b.z * s); v[7] = f2bf(b.w * s);
    return v;
}

// ---------------------------------------------------------------------------
// ONE fused kernel. Block g = scene group g. 512 threads = 8 waves.
//
// R10: packed-math VALU-op reduction. R9 counters proved the kernel is
// VALU-throughput-bound (VALUBusy 69%, MfmaUtil 17%) and NOT occupancy-bound
// (4 blocks/CU fit at LDS=40960 with zero dur change vs 3). So: rewrite the
// hot arithmetic as float2 VOP3P packed ops (v_pk_add/mul/max/fma_f32) and
// replace the 3-op manual bf16 RNE with single-op v_cvt_pk_bf16_f32 pairs
// (bitwise-identical rounding). Applied to: spatial A-frag build (largest),
// GRU gate math (trans ops stay scalar - no pk exp2/rcp), emb build, su prep.
// Per-element arithmetic is bit-identical; only the spatial acc pairing
// reassociates 2 fp32 adds (~1e-6 vs 0.0156 tol).
// Structure/LDS/barriers/launch_bounds(512,4) unchanged from R9.
// Sentinel: VGPR_Count > 64 => pk reg-pair pressure broke the allocation.
//
// LDS layout (40960 B): Hf single-buffered (2 barriers/step); scene staged
// transiently in Hf bytes pre-loop, re-gathered from L2 post-loop.
// Phase 1 (GRU): waves 0-3 fwd, 4-7 bwd; wave wd owns gate cols [16wd,16wd+16).
//   B-frags pre-scaled by -1/ln2 (r,z) / 2/ln2 (n); biases added as scalars
//   after the MFMA. sigma(x)=rcp(1+exp2(-x/ln2)), tanh(t)=1-2*rcp(exp2(2t/ln2)+1).
//   Hf write slot permuted (slot = qa*16 + r*4 + quad); reads use rlane.
// Phase 2 (spatial MFMA) + Phase 3 (head): R6 structure; spatial arrays
//   overlay dead Xall in a union; Hf region preserved for epilogue.
// ---------------------------------------------------------------------------
__global__ __launch_bounds__(512, 4) void fused_kernel(
    const float* __restrict__ scene, const int* __restrict__ index_div,
    const float* __restrict__ W_emb, const float* __restrict__ b_emb,
    const float* __restrict__ Wih_f, const float* __restrict__ Whh_f,
    const float* __restrict__ bih_f, const float* __restrict__ bhh_f,
    const float* __restrict__ Wih_b, const float* __restrict__ Whh_b,
    const float* __restrict__ bih_b, const float* __restrict__ bhh_b,
    const float* __restrict__ Wm, const float* __restrict__ bm,
    const float* __restrict__ Ws1, const float* __restrict__ bs1,
    const float* __restrict__ Ws2, const float* __restrict__ bs2,
    const float* __restrict__ Wo1, const float* __restrict__ bo1,
    const float* __restrict__ Wo2, const float* __restrict__ bo2,
    float* __restrict__ full_enc, float* __restrict__ out)
{
    __shared__ __align__(16) union SmemU {
        struct {                                     // GRU phase: 40960 B exactly
            short Xall[16 * 2 * 64 * 8];             // [t][mt][lane][8]      32768 B
            short Hf[2 * 2 * 2 * 64 * 8];            // [dir][ks][mt][slot][8] 8192 B (single buf)
        } g;
        struct {                                     // spatial/head phase (25856 B < 32768 B)
            float su[NGRP][68];                      //  8704 B
            float fe[NGRP][68];                      //  8704 B
            float swo1[1024];                        //  4096 B
            float szero[32];                         //   128 B
            float sscene2[32][33];                   //  4224 B  (re-gathered scene, [c][veh])
        } s;
    } sm;

    const int g    = blockIdx.x;
    const int tid  = threadIdx.x;
    const int lane = tid & 63;
    const int w    = __builtin_amdgcn_readfirstlane(tid >> 6);  // 0..7
    const int dir  = w >> 2;
    const int wd   = w & 3;
    const int cc   = lane & 15;
    const int quad = lane >> 4;
    const int j    = wd * 16 + cc;            // gate column
    const int ks_w = j >> 5;
    const int qa_w = (j >> 3) & 3;
    const int ii_w = j & 7;
    // permuted reader lane: slot(Lq, m) = Lq*16 + (m&3)*4 + (m>>2)
    const int rlane = (lane & 48) | ((lane & 3) << 2) | ((lane >> 2) & 3);

    // ---- stage gathered scene rows into the (not-yet-live) Hf bytes as
    //      float sc0[32][33] (4224 B <= 8192 B) ----
    {
        float* sc0 = (float*)sm.g.Hf;
        #pragma unroll
        for (int rep = 0; rep < 2; ++rep) {
            const int idx = tid + rep * 512;
            const int v = idx >> 5, c = idx & 31;
            const int n = index_div[g * NGRP + v];
            sc0[c * 33 + v] = scene[n * 32 + c];
        }
    }

    // ---- per-wave GRU B-frags, pre-scaled; biases stay SCALAR ----
    const float* Wih = dir ? Wih_b : Wih_f;
    const float* Whh = dir ? Whh_b : Whh_f;
    const float* bih = dir ? bih_b : bih_f;
    const float* bhh = dir ? bhh_b : bhh_f;
    const int k0 = quad * 8;
    const float SRZ = -RLN2, SN = 2.0f * RLN2;
    const short8 Br0  = ld8bfs(Whh + (j      ) * 64 + k0,      SRZ);
    const short8 Br1  = ld8bfs(Whh + (j      ) * 64 + 32 + k0, SRZ);
    const short8 Br2  = ld8bfs(Wih + (j      ) * 32 + k0,      SRZ);
    const short8 Bz0  = ld8bfs(Whh + (j +  64) * 64 + k0,      SRZ);
    const short8 Bz1  = ld8bfs(Whh + (j +  64) * 64 + 32 + k0, SRZ);
    const short8 Bz2  = ld8bfs(Wih + (j +  64) * 32 + k0,      SRZ);
    const short8 Bhn0 = ld8bfs(Whh + (j + 128) * 64 + k0,      SN);
    const short8 Bhn1 = ld8bfs(Whh + (j + 128) * 64 + 32 + k0, SN);
    const short8 Bxn  = ld8bfs(Wih + (j + 128) * 32 + k0,      SN);
    const float vb_r  = SRZ * (bih[j] + bhh[j]);
    const float vb_z  = SRZ * (bih[j + 64] + bhh[j + 64]);
    const float vb_xn = SN * bih[j + 128];
    const float vb_hn = SN * bhh[j + 128];
    const float2v vbr2  = mk2(vb_r,  vb_r);
    const float2v vbz2  = mk2(vb_z,  vb_z);
    const float2v vbxn2 = mk2(vb_xn, vb_xn);
    const float2v vbhn2 = mk2(vb_hn, vb_hn);

    __syncthreads();   // sc0 ready

    // ---- emb for ALL t (512 threads = 16 t x 32 veh), packed math ----
    {
        const float* sc0 = (const float*)sm.g.Hf;
        const int tt  = tid >> 5;
        const int veh = tid & 31;
        const float xs = sc0[tt * 33 + veh];
        const float ys = sc0[(16 + tt) * 33 + veh];
        const float2v xs2 = mk2(xs, xs), ys2 = mk2(ys, ys);
        const int mt = veh >> 4;
        const int m  = veh & 15;
        #pragma unroll
        for (int q = 0; q < 4; ++q) {
            uint4v au;
            #pragma unroll
            for (int pp = 0; pp < 4; ++pp) {
                const int e = q * 8 + pp * 2;
                const float2v w1 = *(const float2v*)&W_emb[e];
                const float2v w2 = *(const float2v*)&W_emb[EE + e];
                const float2v bb = *(const float2v*)&b_emb[e];
                float2v t = __builtin_elementwise_fma(ys2, w2, bb);   // v_pk_fma
                t = __builtin_elementwise_fma(xs2, w1, t);            // v_pk_fma
                au[pp] = cvtpk2(leaky2(t));
            }
            *(short8*)&sm.g.Xall[(((tt * 2 + mt) * 64) + q * 16 + m) * 8] =
                __builtin_bit_cast(short8, au);
        }
    }
    __syncthreads();   // all sc0 reads consumed -> Hf bytes reusable
    {
        const short8 z8 = {0, 0, 0, 0, 0, 0, 0, 0};
        *(short8*)&sm.g.Hf[tid * 8] = z8;     // zero all 4096 shorts (both dirs)
    }

    float h_reg[8];
    #pragma unroll
    for (int i = 0; i < 8; ++i) h_reg[i] = 0.0f;

    const int hf_dir = dir * 2048;                 // shorts (dir stride, single buf)
    __syncthreads();   // Hf zeroed

    // ---- GRU main loop: single-buffered Hf, TWO barriers per step ----
    #pragma unroll 2
    for (int s = 0; s < TT; ++s) {
        const int t  = dir ? (TT - 1 - s) : s;
        const short* HfD = &sm.g.Hf[hf_dir];
        #pragma unroll
        for (int mt = 0; mt < 2; ++mt) {
            const short8 Ah0 = *(const short8*)&HfD[((0 * 2 + mt) * 64 + rlane) * 8];
            const short8 Ah1 = *(const short8*)&HfD[((1 * 2 + mt) * 64 + rlane) * 8];
            const short8 Axx = *(const short8*)&sm.g.Xall[((t * 2 + mt) * 64 + lane) * 8];
            const floatx4 z4 = {0.f, 0.f, 0.f, 0.f};
            const floatx4 ar  = MFMA16(Axx, Br2, MFMA16(Ah1, Br1, MFMA16(Ah0, Br0, z4)));
            const floatx4 az  = MFMA16(Axx, Bz2, MFMA16(Ah1, Bz1, MFMA16(Ah0, Bz0, z4)));
            const floatx4 ahn = MFMA16(Ah1, Bhn1, MFMA16(Ah0, Bhn0, z4));
            const floatx4 axn = MFMA16(Axx, Bxn, z4);
            // gate math on r-pairs: pk adds/fmas, scalar trans (no pk exp2/rcp).
            // Per-element ops identical to scalar version -> bitwise identical.
            #pragma unroll
            for (int rp = 0; rp < 2; ++rp) {
                const float2v arp = mk2(ar[2 * rp], ar[2 * rp + 1]) + vbr2;
                const float2v azp = mk2(az[2 * rp], az[2 * rp + 1]) + vbz2;
                const float2v er1 = mk2(__builtin_amdgcn_exp2f(arp.x),
                                        __builtin_amdgcn_exp2f(arp.y)) + 1.0f;
                const float2v ez1 = mk2(__builtin_amdgcn_exp2f(azp.x),
                                        __builtin_amdgcn_exp2f(azp.y)) + 1.0f;
                const float2v rr = mk2(__builtin_amdgcn_rcpf(er1.x),
                                       __builtin_amdgcn_rcpf(er1.y));
                const float2v zz = mk2(__builtin_amdgcn_rcpf(ez1.x),
                                       __builtin_amdgcn_rcpf(ez1.y));
                const float2v hnp = mk2(ahn[2 * rp], ahn[2 * rp + 1]) + vbhn2;
                const float2v xnp = mk2(axn[2 * rp], axn[2 * rp + 1]) + vbxn2;
                const float2v y   = __builtin_elementwise_fma(rr, hnp, xnp);
                const float2v ey1 = mk2(__builtin_amdgcn_exp2f(y.x),
                                        __builtin_amdgcn_exp2f(y.y)) + 1.0f;
                const float2v tq  = mk2(__builtin_amdgcn_rcpf(ey1.x),
                                        __builtin_amdgcn_rcpf(ey1.y));
                const float2v ng  = __builtin_elementwise_fma(mk2(-2.f, -2.f), tq,
                                                              mk2(1.f, 1.f));
                const float2v h0  = mk2(h_reg[mt * 4 + 2 * rp], h_reg[mt * 4 + 2 * rp + 1]);
                const float2v hn  = __builtin_elementwise_fma(zz, h0 - ng, ng);
                h_reg[mt * 4 + 2 * rp]     = hn.x;
                h_reg[mt * 4 + 2 * rp + 1] = hn.y;
            }
        }
        __syncthreads();   // all waves' Hf reads complete -> in-place write safe
        short* HfW = &sm.g.Hf[hf_dir];
        #pragma unroll
        for (int mt = 0; mt < 2; ++mt) {
            #pragma unroll
            for (int r = 0; r < 4; ++r) {
                const int slot = qa_w * 16 + r * 4 + quad;   // perm of qa*16 + m
                HfW[((ks_w * 2 + mt) * 64 + slot) * 8 + ii_w] = f2bf_h(h_reg[mt * 4 + r]);
            }
        }
        __syncthreads();   // writes visible for next step
    }
    // Final h in Hf[dir]. Xall dead from here.

    // ---- re-gather scene into spatial union region (L2-hot; HBM idle) ----
    #pragma unroll
    for (int rep = 0; rep < 2; ++rep) {
        const int idx = tid + rep * 512;
        const int v = idx >> 5, c = idx & 31;
        const int n = index_div[g * NGRP + v];
        sm.s.sscene2[c][v] = scene[n * 32 + c];
    }
    __syncthreads();   // sscene2 ready

    // ---- Phase 2 prep: waves 0-3 seq_enc epilogue; waves 4-7 su/swo1/szero ----
    if (w < 4) {
        const int nt   = w >> 1;
        const int mt_e = w & 1;
        const int n_col = nt * 16 + cc;
        short8 Bm0, Bm1;
        #pragma unroll
        for (int i = 0; i < 8; ++i) {
            Bm0[i] = f2bf(Wm[(     quad * 8 + i) * 32 + n_col]);
            Bm1[i] = f2bf(Wm[(32 + quad * 8 + i) * 32 + n_col]);
        }
        short8 A0, A1;
        #pragma unroll
        for (int ks = 0; ks < 2; ++ks) {
            const short8 F = *(const short8*)&sm.g.Hf[0    + ((ks * 2 + mt_e) * 64 + rlane) * 8];
            const short8 B = *(const short8*)&sm.g.Hf[2048 + ((ks * 2 + mt_e) * 64 + rlane) * 8];
            #pragma unroll
            for (int i = 0; i < 8; ++i) {
                const short v = f2bf(0.5f * (bf2f(F[i]) + bf2f(B[i])));
                if (ks == 0) A0[i] = v; else A1[i] = v;
            }
        }
        const floatx4 z4 = {0.f, 0.f, 0.f, 0.f};
        const floatx4 acc = MFMA16(A1, Bm1, MFMA16(A0, Bm0, z4));
        const float bmn = bm[n_col];
        #pragma unroll
        for (int r = 0; r < 4; ++r) {
            const int veh = mt_e * 16 + quad * 4 + r;
            const float sv = leakyf(acc[r] + bmn);
            const int n = index_div[g * NGRP + veh];
            full_enc[n * HH + n_col] = sv;
            sm.s.fe[veh][n_col] = sv;     // fe region does not overlap Hf
        }
    } else {
        const int l  = tid & 255;
        const int v  = l >> 3;
        const int d0 = (l & 7) * 8;
        float2v acc2[4];
        #pragma unroll
        for (int i = 0; i < 4; ++i) acc2[i] = mk2(0.f, 0.f);
        #pragma unroll
        for (int e = 0; e < EE; ++e) {
            const float f = sm.s.sscene2[e][v];
            const float2v ff = mk2(f, f);
            const float4 w0 = *(const float4*)&Ws1[e * 64 + d0];
            const float4 w1 = *(const float4*)&Ws1[e * 64 + d0 + 4];
            acc2[0] = __builtin_elementwise_fma(ff, mk2(w0.x, w0.y), acc2[0]);
            acc2[1] = __builtin_elementwise_fma(ff, mk2(w0.z, w0.w), acc2[1]);
            acc2[2] = __builtin_elementwise_fma(ff, mk2(w1.x, w1.y), acc2[2]);
            acc2[3] = __builtin_elementwise_fma(ff, mk2(w1.z, w1.w), acc2[3]);
        }
        float4 st0, st1;
        st0.x = acc2[0].x; st0.y = acc2[0].y; st0.z = acc2[1].x; st0.w = acc2[1].y;
        st1.x = acc2[2].x; st1.y = acc2[2].y; st1.z = acc2[3].x; st1.w = acc2[3].y;
        *(float4*)&sm.s.su[v][d0]     = st0;
        *(float4*)&sm.s.su[v][d0 + 4] = st1;
        *(float4*)&sm.s.swo1[l * 4] = *(const float4*)&Wo1[l * 4];
        if (l < 32) {
            float zs = bs2[l];
            #pragma unroll
            for (int d = 0; d < HH; ++d) zs = fmaf(leakyf(bs1[d]), Ws2[d * 32 + l], zs);
            sm.s.szero[l] = leakyf(zs);
        }
    }

    // ---- spatial B-frags (all 8 waves) ----
    short8 Bw00, Bw01, Bw10, Bw11;
    #pragma unroll
    for (int i = 0; i < 8; ++i) {
        Bw00[i] = f2bf(Ws2[(     quad * 8 + i) * 32 + cc]);
        Bw01[i] = f2bf(Ws2[(32 + quad * 8 + i) * 32 + cc]);
        Bw10[i] = f2bf(Ws2[(     quad * 8 + i) * 32 + 16 + cc]);
        Bw11[i] = f2bf(Ws2[(32 + quad * 8 + i) * 32 + 16 + cc]);
    }
    float2v bsq0v[4], bsq1v[4];
    #pragma unroll
    for (int i = 0; i < 4; ++i) {
        bsq0v[i] = *(const float2v*)&bs1[quad * 8 + 2 * i];
        bsq1v[i] = *(const float2v*)&bs1[32 + quad * 8 + 2 * i];
    }
    const float2v bs02 = mk2(bs2[cc], bs2[cc]);
    const float2v bs12 = mk2(bs2[16 + cc], bs2[16 + cc]);
    __syncthreads();

    // ---- spatial pairwise MLP: 8 waves x 4 j's, packed A-build ----
    #pragma unroll 2
    for (int jj = 0; jj < 4; ++jj) {
        const int jrow = w * 4 + jj;       // wave-uniform j, 0..31
        float2v vj0v[4], vj1v[4];
        {
            const float4 q0 = *(const float4*)&sm.s.su[jrow][quad * 8];
            const float4 q1 = *(const float4*)&sm.s.su[jrow][quad * 8 + 4];
            const float4 q2 = *(const float4*)&sm.s.su[jrow][32 + quad * 8];
            const float4 q3 = *(const float4*)&sm.s.su[jrow][32 + quad * 8 + 4];
            vj0v[0] = mk2(q0.x, q0.y) - bsq0v[0];
            vj0v[1] = mk2(q0.z, q0.w) - bsq0v[1];
            vj0v[2] = mk2(q1.x, q1.y) - bsq0v[2];
            vj0v[3] = mk2(q1.z, q1.w) - bsq0v[3];
            vj1v[0] = mk2(q2.x, q2.y) - bsq1v[0];
            vj1v[1] = mk2(q2.z, q2.w) - bsq1v[1];
            vj1v[2] = mk2(q3.x, q3.y) - bsq1v[2];
            vj1v[3] = mk2(q3.z, q3.w) - bsq1v[3];
        }
        float2v acc0v = mk2(0.f, 0.f), acc1v = mk2(0.f, 0.f);
        #pragma unroll
        for (int it = 0; it < 2; ++it) {
            const int irow = it * 16 + cc;   // A-frag row m = cc
            const float4 p0 = *(const float4*)&sm.s.su[irow][quad * 8];
            const float4 p1 = *(const float4*)&sm.s.su[irow][quad * 8 + 4];
            const float4 p2 = *(const float4*)&sm.s.su[irow][32 + quad * 8];
            const float4 p3 = *(const float4*)&sm.s.su[irow][32 + quad * 8 + 4];
            uint4v a0u, a1u;
            a0u[0] = cvtpk2(leaky2(mk2(p0.x, p0.y) - vj0v[0]));
            a0u[1] = cvtpk2(leaky2(mk2(p0.z, p0.w) - vj0v[1]));
            a0u[2] = cvtpk2(leaky2(mk2(p1.x, p1.y) - vj0v[2]));
            a0u[3] = cvtpk2(leaky2(mk2(p1.z, p1.w) - vj0v[3]));
            a1u[0] = cvtpk2(leaky2(mk2(p2.x, p2.y) - vj1v[0]));
            a1u[1] = cvtpk2(leaky2(mk2(p2.z, p2.w) - vj1v[1]));
            a1u[2] = cvtpk2(leaky2(mk2(p3.x, p3.y) - vj1v[2]));
            a1u[3] = cvtpk2(leaky2(mk2(p3.z, p3.w) - vj1v[3]));
            const short8 A0 = __builtin_bit_cast(short8, a0u);
            const short8 A1 = __builtin_bit_cast(short8, a1u);
            const floatx4 z4 = {0.f, 0.f, 0.f, 0.f};
            const floatx4 D0 = MFMA16(A1, Bw01, MFMA16(A0, Bw00, z4));
            const floatx4 D1 = MFMA16(A1, Bw11, MFMA16(A0, Bw10, z4));
            acc0v += leaky2(mk2(D0[0], D0[1]) + bs02);
            acc0v += leaky2(mk2(D0[2], D0[3]) + bs02);
            acc1v += leaky2(mk2(D1[0], D1[1]) + bs12);
            acc1v += leaky2(mk2(D1[2], D1[3]) + bs12);
        }
        float acc0 = acc0v.x + acc0v.y;
        float acc1 = acc1v.x + acc1v.y;
        acc0 += __shfl_xor(acc0, 16, 64); acc0 += __shfl_xor(acc0, 32, 64);
        acc1 += __shfl_xor(acc1, 16, 64); acc1 += __shfl_xor(acc1, 32, 64);
        const int n = index_div[g * NGRP + jrow];
        if (quad == 0) {
            const float pv = (acc0 - sm.s.szero[cc]) * (1.0f / 31.0f);
            full_enc[n * HH + 32 + cc] = pv;
            sm.s.fe[jrow][32 + cc] = pv;
        } else if (quad == 1) {
            const float pv = (acc1 - sm.s.szero[16 + cc]) * (1.0f / 31.0f);
            full_enc[n * HH + 48 + cc] = pv;
            sm.s.fe[jrow][48 + cc] = pv;
        }
    }
    __syncthreads();

    // ---- head: x_logit = leaky(fe @ Wo1 + bo1) @ Wo2 + bo2 ----
    {
        const int veh = tid >> 4;          // 0..31
        const int p   = tid & 15;          // hidden dim
        float a = bo1[p];
        #pragma unroll
        for (int k = 0; k < HH; ++k)
            a = fmaf(sm.s.fe[veh][k], sm.s.swo1[k * 16 + p], a);
        a = leakyf(a);
        float l0 = a * Wo2[p * 3 + 0];
        float l1 = a * Wo2[p * 3 + 1];
        float l2 = a * Wo2[p * 3 + 2];
        #pragma unroll
        for (int off = 1; off < 16; off <<= 1) {
            l0 += __shfl_xor(l0, off, 64);
            l1 += __shfl_xor(l1, off, 64);
            l2 += __shfl_xor(l2, off, 64);
        }
        if (p == 0) {
            const int n = index_div[g * NGRP + veh];
            out[n * 3 + 0] = l0 + bo2[0];
            out[n * 3 + 1] = l1 + bo2[1];
            out[n * 3 + 2] = l2 + bo2[2];
        }
    }
}

// ---------------------------------------------------------------------------
extern "C" void kernel_launch(void* const* d_in, const int* in_sizes, int n_in,
                              void* d_out, int out_size, void* d_ws, size_t ws_size,
                              hipStream_t stream) {
    const float* scene     = (const float*)d_in[0];
    const int*   index_div = (const int*)d_in[4];
    const float* W_emb = (const float*)d_in[5];
    const float* b_emb = (const float*)d_in[6];
    const float* Wih_f = (const float*)d_in[7];
    const float* Whh_f = (const float*)d_in[8];
    const float* bih_f = (const float*)d_in[9];
    const float* bhh_f = (const float*)d_in[10];
    const float* Wih_b = (const float*)d_in[11];
    const float* Whh_b = (const float*)d_in[12];
    const float* bih_b = (const float*)d_in[13];
    const float* bhh_b = (const float*)d_in[14];
    const float* Wm  = (const float*)d_in[15];
    const float* bm  = (const float*)d_in[16];
    const float* Ws1 = (const float*)d_in[17];
    const float* bs1 = (const float*)d_in[18];
    const float* Ws2 = (const float*)d_in[19];
    const float* bs2 = (const float*)d_in[20];
    const float* Wo1 = (const float*)d_in[21];
    const float* bo1 = (const float*)d_in[22];
    const float* Wo2 = (const float*)d_in[23];
    const float* bo2 = (const float*)d_in[24];

    const int N = in_sizes[0] / (2 * TT);   // 32768
    const int G = in_sizes[4] / NGRP;       // 1024

    float* out      = (float*)d_out;
    float* full_enc = out + (size_t)N * CC;

    fused_kernel<<<dim3(G), dim3(512), 0, stream>>>(
        scene, index_div, W_emb, b_emb, Wih_f, Whh_f, bih_f, bhh_f,
        Wih_b, Whh_b, bih_b, bhh_b, Wm, bm, Ws1, bs1, Ws2, bs2,
        Wo1, bo1, Wo2, bo2, full_enc, out);
}